// Round 6
// baseline (101.102 us; speedup 1.0000x reference)
//
#include <hip/hip_runtime.h>

typedef __attribute__((ext_vector_type(8))) short bf16x8;
typedef __attribute__((ext_vector_type(4))) float f32x4;

__device__ __forceinline__ unsigned short f2bf(float f) {
  union { float f; unsigned int u; } v; v.f = f;
  return (unsigned short)((v.u + 0x7fffu + ((v.u >> 16) & 1u)) >> 16);
}

// cu_comp: np-ref convention cu_seqlens[i] // STRIDE, as f32
__global__ void cu_kernel(const int* __restrict__ cu_in, float* __restrict__ out,
                          int cubase, int nb, int strideh) {
  int t = threadIdx.x;
  if (t <= nb) out[cubase + t] = (float)(cu_in[t] / strideh);
}

// prep: f32 weights -> bf16 XOR-swizzled per-K-step images.
// img[s][o*64+c] = bf16( w[o][ (s&1)*64 + (c ^ ((o&7)<<3)) ][ s>>1 ] ), s = 2t+half
__global__ __launch_bounds__(256) void prep_kernel(
    const float* __restrict__ kw, const float* __restrict__ vw,
    unsigned short* __restrict__ imgK, unsigned short* __restrict__ imgV, int KSd) {
  __shared__ float wlds[4096];
  int tid = threadIdx.x, bid = blockIdx.x;
  int sel = bid >> 7, o = bid & 127;
  int nel = 128 * KSd;
  const float* wo = (sel ? vw : kw) + (size_t)o * nel;
  unsigned short* dst = sel ? imgV : imgK;
  for (int i = tid; i < (nel >> 2); i += 256)
    ((float4*)wlds)[i] = ((const float4*)wo)[i];
  __syncthreads();
  int swE = (o & 7) << 3;
  for (int idx = tid; idx < nel; idx += 256) {
    int s = idx >> 6, c = idx & 63;
    int i = ((s & 1) << 6) + (c ^ swE);
    dst[((size_t)s << 13) + (o << 6) + c] = f2bf(wlds[i * KSd + (s >> 1)]);
  }
}

// gemm: one (sel, h, 64-row M-tile) per block; 512 thr = 8 waves (2M x 4N);
// wave owns 32x32 output via 2x2 fragments of 16x16x32 bf16 MFMA; K = 128*KS.
// Output stores are F32.
__global__ __launch_bounds__(512) void gemm_kernel(
    const float* __restrict__ kv,
    const float* __restrict__ biasK, const float* __restrict__ biasV,
    const unsigned short* __restrict__ imgK, const unsigned short* __restrict__ imgV,
    const float* __restrict__ kw, const float* __restrict__ vw,
    float* __restrict__ out,
    int selbase, int vbase, int nc, int ltot, int nsteps,
    int tokmax, int seqb, int strideh, int KSd, int mtiles) {
  __shared__ __align__(16) unsigned short As[2][4096];   // 64 x 64 bf16, swizzled
  __shared__ __align__(16) unsigned short Bs[2][8192];   // 128 x 64 bf16, pre-swizzled
  int tid = threadIdx.x, bid = blockIdx.x;
  int per_sel = 8 * mtiles;
  int sel = selbase + (bid >= per_sel);
  int rem = (bid >= per_sel) ? bid - per_sel : bid;
  int h = rem / mtiles, mtile = rem - h * mtiles;
  int m0 = mtile * 64;
  const unsigned short* img = sel ? imgV : imgK;
  const float* bias = sel ? biasV : biasK;
  const float* wsel = sel ? vw : kw;
  int outbase = sel ? vbase : 0;
  int lane = tid & 63, wid = tid >> 6;
  int warpM = wid >> 2, warpN = wid & 3;

  // ---- A staging: 8 threads/row, row r per thread-octet ----
  int aj = tid & 7, r = tid >> 3;
  int l = m0 + r; if (l > ltot - 1) l = ltot - 1;   // clamped read, guarded write
  int b = l / nc, c = l - b * nc;
  int btok = b * seqb + c * strideh;
  const float* abase = kv + sel * 1024 + h * 128 + aj * 4;
  int swr = (r & 7) << 3;
  int awb0 = r * 128 + 2 * ((aj * 4) ^ swr);
  int awb1 = r * 128 + 2 * ((aj * 4 + 32) ^ swr);

  // ---- gather-fallback (img==null) per-thread constants ----
  int o_g = tid >> 3, cb_g = (tid & 7) << 3;
  int ib_g = cb_g ^ ((o_g & 7) << 3);
  const float* g0 = wsel + (size_t)o_g * (KSd << 7);
  const float* g1 = g0 + ((size_t)64 * (KSd << 7));

  // ---- compute-side fragment constants (bytes) ----
  int kb0 = (lane >> 4) * 16;
  int arb[2], asw[2], brb[2], bsw[2];
#pragma unroll
  for (int mi = 0; mi < 2; ++mi) {
    int rr = warpM * 32 + mi * 16 + (lane & 15);
    arb[mi] = rr * 128; asw[mi] = (rr & 7) << 4;
  }
#pragma unroll
  for (int ni = 0; ni < 2; ++ni) {
    int oo = warpN * 32 + ni * 16 + (lane & 15);
    brb[ni] = oo * 128; bsw[ni] = (oo & 7) << 4;
  }

  f32x4 acc[2][2];
  f32x4 zz = {0.f, 0.f, 0.f, 0.f};
#pragma unroll
  for (int a = 0; a < 2; ++a)
#pragma unroll
    for (int b2 = 0; b2 < 2; ++b2) acc[a][b2] = zz;

  float4 Af0, Af1;
  uint4 Br[2];

#define LOAD_STEP(S) do {                                                        \
    int tok_ = btok + ((S) >> 1); if (tok_ > tokmax) tok_ = tokmax;              \
    const float* ap_ = abase + ((size_t)tok_ << 11) + (((S) & 1) << 6);          \
    Af0 = *(const float4*)ap_;                                                   \
    Af1 = *(const float4*)(ap_ + 32);                                            \
    if (img) {                                                                   \
      const uint4* bsrc_ = (const uint4*)(img + ((size_t)(S) << 13));            \
      Br[0] = bsrc_[tid];                                                        \
      Br[1] = bsrc_[512 + tid];                                                  \
    } else {                                                                     \
      int t_ = (S) >> 1, i0_ = (((S) & 1) << 6) + ib_g;                          \
      unsigned int p0_[4], p1_[4];                                               \
      _Pragma("unroll")                                                          \
      for (int m = 0; m < 4; ++m) {                                              \
        p0_[m] = (unsigned int)f2bf(g0[(i0_ + 2*m) * KSd + t_])                  \
               | ((unsigned int)f2bf(g0[(i0_ + 2*m + 1) * KSd + t_]) << 16);     \
        p1_[m] = (unsigned int)f2bf(g1[(i0_ + 2*m) * KSd + t_])                  \
               | ((unsigned int)f2bf(g1[(i0_ + 2*m + 1) * KSd + t_]) << 16);     \
      }                                                                          \
      Br[0] = make_uint4(p0_[0], p0_[1], p0_[2], p0_[3]);                        \
      Br[1] = make_uint4(p1_[0], p1_[1], p1_[2], p1_[3]);                        \
    }                                                                            \
  } while (0)

#define WRITE_STEP(DB) do {                                                      \
    unsigned int lo0_ = (unsigned int)f2bf(Af0.x) | ((unsigned int)f2bf(Af0.y) << 16); \
    unsigned int hi0_ = (unsigned int)f2bf(Af0.z) | ((unsigned int)f2bf(Af0.w) << 16); \
    unsigned int lo1_ = (unsigned int)f2bf(Af1.x) | ((unsigned int)f2bf(Af1.y) << 16); \
    unsigned int hi1_ = (unsigned int)f2bf(Af1.z) | ((unsigned int)f2bf(Af1.w) << 16); \
    *(uint2*)((char*)As[DB] + awb0) = make_uint2(lo0_, hi0_);                    \
    *(uint2*)((char*)As[DB] + awb1) = make_uint2(lo1_, hi1_);                    \
    uint4* bdst_ = (uint4*)Bs[DB];                                               \
    bdst_[tid] = Br[0];                                                          \
    bdst_[512 + tid] = Br[1];                                                    \
  } while (0)

#define COMPUTE_STEP(CB) do {                                                    \
    _Pragma("unroll")                                                            \
    for (int kk = 0; kk < 2; ++kk) {                                             \
      bf16x8 af_[2], bg_[2];                                                     \
      int kc_ = kk * 64 + kb0;                                                   \
      _Pragma("unroll")                                                          \
      for (int mi = 0; mi < 2; ++mi)                                             \
        af_[mi] = *(const bf16x8*)((const char*)As[CB] + arb[mi] + (kc_ ^ asw[mi])); \
      _Pragma("unroll")                                                          \
      for (int ni = 0; ni < 2; ++ni)                                             \
        bg_[ni] = *(const bf16x8*)((const char*)Bs[CB] + brb[ni] + (kc_ ^ bsw[ni])); \
      _Pragma("unroll")                                                          \
      for (int mi = 0; mi < 2; ++mi)                                             \
      _Pragma("unroll")                                                          \
        for (int ni = 0; ni < 2; ++ni)                                           \
          acc[mi][ni] = __builtin_amdgcn_mfma_f32_16x16x32_bf16(af_[mi], bg_[ni], acc[mi][ni], 0, 0, 0); \
    }                                                                            \
  } while (0)

  LOAD_STEP(0);
  WRITE_STEP(0);
  __syncthreads();
  int cur = 0;
  for (int s = 0; s < nsteps; ++s) {
    if (s + 1 < nsteps) LOAD_STEP(s + 1);   // issue next-step loads early
    COMPUTE_STEP(cur);
    if (s + 1 < nsteps) WRITE_STEP(cur ^ 1);
    __syncthreads();
    cur ^= 1;
  }

  // ---- epilogue: bias + F32 store (guarded) ----
  int l15 = lane & 15, l4 = lane >> 4;
#pragma unroll
  for (int ni = 0; ni < 2; ++ni) {
    int o = warpN * 32 + ni * 16 + l15;
    float bv = bias[o];
#pragma unroll
    for (int mi = 0; mi < 2; ++mi) {
      int lb = m0 + warpM * 32 + mi * 16 + l4 * 4;
      f32x4 v = acc[mi][ni];
#pragma unroll
      for (int jj = 0; jj < 4; ++jj) {
        int ll = lb + jj;
        if (ll < ltot)
          out[(size_t)outbase + (size_t)ll * 1024 + h * 128 + o] = v[jj] + bv;
      }
    }
  }
}

extern "C" void kernel_launch(void* const* d_in, const int* in_sizes, int n_in,
                              void* d_out, int out_size, void* d_ws, size_t ws_size,
                              hipStream_t stream) {
  // ---- identify inputs by element count (robust to order) ----
  long kvN = 0; int kvi = 0;
  for (int i = 0; i < n_in; ++i)
    if ((long)in_sizes[i] > kvN) { kvN = in_sizes[i]; kvi = i; }
  const float* kv = (const float*)d_in[kvi];
  const float *w0 = nullptr, *w1 = nullptr, *b0 = nullptr, *b1 = nullptr;
  const int* cuin = nullptr;
  int KSd = 32, nb = 4;
  for (int i = 0; i < n_in; ++i) {
    if (i == kvi) continue;
    int sz = in_sizes[i];
    if (sz == 128) { if (!b0) b0 = (const float*)d_in[i]; else if (!b1) b1 = (const float*)d_in[i]; }
    else if (sz <= 32) { nb = sz - 1; cuin = (const int*)d_in[i]; }
    else if (sz >= 4096) {
      if (!w0) { w0 = (const float*)d_in[i]; KSd = sz / 16384; }
      else if (!w1) w1 = (const float*)d_in[i];
    }
  }
  if (!w0) w0 = (const float*)d_in[2];
  if (!b0) b0 = (const float*)d_in[3];
  if (!w1) w1 = (const float*)d_in[4];
  if (!b1) b1 = (const float*)d_in[5];
  if (!cuin) cuin = (const int*)d_in[1];
  if (nb < 1) nb = 4;

  float* out = (float*)d_out;

  // ---- geometry fully derived from reported sizes ----
  int cubase  = out_size - (nb + 1);     // 4186112
  int vbase   = cubase >> 1;             // 2093056
  int ltot    = cubase >> 11;            // 2044
  int nc      = ltot / nb;               // 511
  int nsteps  = 2 * KSd;                 // 64
  long tokens = kvN >> 11;               // 32768
  int seqb    = (int)(tokens / nb);      // 8192
  int strideh = (nc > 1) ? (seqb - KSd) / (nc - 1) : KSd;   // 16
  int tokmax  = (int)tokens - 1;
  int mtiles  = (ltot + 63) >> 6;        // 32
  int per_sel = 8 * mtiles;              // 256

  cu_kernel<<<1, 64, 0, stream>>>(cuin, out, cubase, nb, strideh);

  size_t imgel = (size_t)nsteps * 8192;  // 524288 bf16 elems per image
  size_t imgbytes = imgel * 2;           // 1 MB
  if (ws_size >= 2 * imgbytes) {
    unsigned short* imgK = (unsigned short*)d_ws;
    unsigned short* imgV = imgK + imgel;
    prep_kernel<<<256, 256, 0, stream>>>(w0, w1, imgK, imgV, KSd);
    gemm_kernel<<<2 * per_sel, 512, 0, stream>>>(kv, b0, b1, imgK, imgV, w0, w1, out,
        0, vbase, nc, ltot, nsteps, tokmax, seqb, strideh, KSd, mtiles);
  } else if (ws_size >= imgbytes && (size_t)vbase * 4 >= imgbytes) {
    // img-K in ws; img-V staged as ushorts in d_out K-region (dead until gemm-K)
    unsigned short* imgK = (unsigned short*)d_ws;
    unsigned short* imgV = (unsigned short*)d_out;
    prep_kernel<<<256, 256, 0, stream>>>(w0, w1, imgK, imgV, KSd);
    gemm_kernel<<<per_sel, 512, 0, stream>>>(kv, b0, b1, imgK, imgV, w0, w1, out,
        1, vbase, nc, ltot, nsteps, tokmax, seqb, strideh, KSd, mtiles);
    gemm_kernel<<<per_sel, 512, 0, stream>>>(kv, b0, b1, imgK, imgV, w0, w1, out,
        0, vbase, nc, ltot, nsteps, tokmax, seqb, strideh, KSd, mtiles);
  } else {
    // no usable scratch: gather B from global weights (L2-resident) each step
    gemm_kernel<<<2 * per_sel, 512, 0, stream>>>(kv, b0, b1,
        (const unsigned short*)nullptr, (const unsigned short*)nullptr, w0, w1, out,
        0, vbase, nc, ltot, nsteps, tokmax, seqb, strideh, KSd, mtiles);
  }
}